// Round 1
// baseline (1608.680 us; speedup 1.0000x reference)
//
#include <hip/hip_runtime.h>
#include <hip/hip_bf16.h>
#include <stdint.h>

// Sparse MoE FFN: N=32768 tokens, D=H=1024, E=8, top-2, fp32 in/out.
// Pipeline: fp32 gate+top2 -> bucket by expert -> bf16 MFMA GEMM1 (relu) ->
// bf16 MFMA GEMM2 -> weighted fp32 atomic scatter-add into zeroed out.

#define NTOK  32768
#define DMODEL 1024
#define HDIM   1024
#define NEXP      8

typedef __bf16 bf16;
typedef __bf16 bf16x4 __attribute__((ext_vector_type(4)));
typedef __bf16 bf16x8 __attribute__((ext_vector_type(8)));
typedef float  f32x4  __attribute__((ext_vector_type(4)));

// ---- workspace layout (bytes), all regions 256B-aligned ----
static constexpr size_t WS_CNT    = 0;                                        // 8 int
static constexpr size_t WS_OFFS   = 256;                                      // 8 int
static constexpr size_t WS_BUCKET = 512;                                      // [E][NTOK] int (entry = tok*2+k)
static constexpr size_t WS_TOPKS  = WS_BUCKET + (size_t)NEXP * NTOK * 4;      // [NTOK*2] float
static constexpr size_t WS_XB     = WS_TOPKS + (size_t)NTOK * 2 * 4;          // x in bf16 [NTOK][D]
static constexpr size_t WS_W1T    = WS_XB  + (size_t)NTOK * DMODEL * 2;       // w1^T bf16 [E][H][D]
static constexpr size_t WS_W2T    = WS_W1T + (size_t)NEXP * DMODEL * HDIM * 2;// w2^T bf16 [E][D][H]
static constexpr size_t WS_H      = WS_W2T + (size_t)NEXP * HDIM * DMODEL * 2;// H bf16 [2N+128][H]
static constexpr size_t WS_END    = WS_H   + (size_t)(2 * NTOK + 128) * HDIM * 2; // ~226 MiB

// async global->LDS, 16B per lane. LDS dest is wave-uniform base + lane*16;
// we pass per-lane &lds[t*8] whose lane-0 value IS the wave base (linear fill).
__device__ __forceinline__ void gload16(const void* g, void* l) {
  __builtin_amdgcn_global_load_lds(
      (const __attribute__((address_space(1))) unsigned int*)(uintptr_t)g,
      (__attribute__((address_space(3))) unsigned int*)(uintptr_t)l,
      16, 0, 0);
}

// ---------------- gating: fp32 scores, exact top-2, bucket build ----------------
__global__ __launch_bounds__(256) void gate_kernel(
    const float* __restrict__ x, const float* __restrict__ gw,
    const float* __restrict__ gb, int* __restrict__ cnt,
    int* __restrict__ bucket, float* __restrict__ topks)
{
  const int lane = threadIdx.x & 63;
  const int tok  = blockIdx.x * 4 + (threadIdx.x >> 6);
  const float* xr = x + (size_t)tok * DMODEL;

  float sc[NEXP];
#pragma unroll
  for (int e = 0; e < NEXP; ++e) sc[e] = 0.f;

  for (int d0 = 0; d0 < DMODEL; d0 += 64) {
    float v = xr[d0 + lane];
    const float* g = gw + (size_t)(d0 + lane) * NEXP;
#pragma unroll
    for (int e = 0; e < NEXP; ++e) sc[e] += v * g[e];
  }
#pragma unroll
  for (int e = 0; e < NEXP; ++e) {
    float a = sc[e];
#pragma unroll
    for (int off = 32; off; off >>= 1) a += __shfl_xor(a, off);
    sc[e] = a + gb[e];
  }

  if (lane == 0) {
    // strict > keeps the lowest index on ties == lax.top_k semantics
    int i1 = 0; float s1 = sc[0];
#pragma unroll
    for (int e = 1; e < NEXP; ++e) if (sc[e] > s1) { s1 = sc[e]; i1 = e; }
    int i2 = (i1 == 0) ? 1 : 0; float s2 = sc[i2];
#pragma unroll
    for (int e = 0; e < NEXP; ++e)
      if (e != i1 && sc[e] > s2) { s2 = sc[e]; i2 = e; }

    int p = atomicAdd(&cnt[i1], 1);
    bucket[i1 * NTOK + p] = tok * 2;
    topks[tok * 2] = s1;
    p = atomicAdd(&cnt[i2], 1);
    bucket[i2 * NTOK + p] = tok * 2 + 1;
    topks[tok * 2 + 1] = s2;
  }
}

__global__ void scan_kernel(const int* __restrict__ cnt, int* __restrict__ offs) {
  if (threadIdx.x == 0) {
    int r = 0;
    for (int e = 0; e < NEXP; ++e) { offs[e] = r; r += cnt[e]; }
  }
}

// ---------------- fp32 -> bf16 converters ----------------
__global__ __launch_bounds__(256) void cvt_x_kernel(
    const float* __restrict__ x, bf16* __restrict__ xb)
{
  const int total = NTOK * DMODEL / 4;
  for (int i = blockIdx.x * blockDim.x + threadIdx.x; i < total;
       i += gridDim.x * blockDim.x) {
    float4 v = ((const float4*)x)[i];
    bf16x4 o = { (bf16)v.x, (bf16)v.y, (bf16)v.z, (bf16)v.w };
    ((bf16x4*)xb)[i] = o;
  }
}

// w[e][k][n] fp32 -> wt[e][n][k] bf16 (transpose so GEMM B-frags are K-contiguous)
__global__ __launch_bounds__(256) void cvt_wt_kernel(
    const float* __restrict__ w, bf16* __restrict__ wt)
{
  __shared__ float tile[32][33];
  const int e  = blockIdx.y;
  const int tk = (blockIdx.x >> 5) * 32;  // source row (k) base
  const int tn = (blockIdx.x & 31) * 32;  // source col (n) base
  const int r  = threadIdx.x >> 3, c4 = (threadIdx.x & 7) * 4;
  const float* we = w + (size_t)e * DMODEL * HDIM;
  float4 v = *(const float4*)&we[(size_t)(tk + r) * 1024 + tn + c4];
  tile[r][c4 + 0] = v.x; tile[r][c4 + 1] = v.y;
  tile[r][c4 + 2] = v.z; tile[r][c4 + 3] = v.w;
  __syncthreads();
  bf16x4 o = { (bf16)tile[c4 + 0][r], (bf16)tile[c4 + 1][r],
               (bf16)tile[c4 + 2][r], (bf16)tile[c4 + 3][r] };
  *(bf16x4*)&wt[(size_t)e * DMODEL * HDIM + (size_t)(tn + r) * 1024 + tk + c4] = o;
}

// ---------------- GEMM1: H = relu(X[bucket] @ W1 + b1), bf16 out ----------------
__global__ __launch_bounds__(256) void gemm1_kernel(
    const bf16* __restrict__ xb, const bf16* __restrict__ w1t,
    const float* __restrict__ b1, const int* __restrict__ cnt,
    const int* __restrict__ offs, const int* __restrict__ bucket,
    bf16* __restrict__ Hbuf)
{
  const int e  = blockIdx.x >> 8;
  const int rb = blockIdx.x & 255;
  const int n  = cnt[e];
  if (rb * 128 >= n) return;
  const int cb = blockIdx.y;

  __shared__ bf16 Al[128 * 32];
  __shared__ bf16 Bl[128 * 32];

  const int t  = threadIdx.x;
  const int r1 = t >> 2, c8 = (t & 3) * 8;
  const int p1 = rb * 128 + r1, p2 = p1 + 64;
  const int ent1 = bucket[e * NTOK + (p1 < n ? p1 : n - 1)];
  const int ent2 = bucket[e * NTOK + (p2 < n ? p2 : n - 1)];
  const bf16* asrc1 = xb + (size_t)(ent1 >> 1) * DMODEL + c8;   // gathered rows
  const bf16* asrc2 = xb + (size_t)(ent2 >> 1) * DMODEL + c8;
  const bf16* bsrc1 = w1t + (size_t)e * DMODEL * HDIM
                    + (size_t)(cb * 128 + r1) * DMODEL + c8;
  const bf16* bsrc2 = bsrc1 + (size_t)64 * DMODEL;
  bf16* al_dst = &Al[t * 8];
  bf16* bl_dst = &Bl[t * 8];

  const int lane = t & 63, wv = t >> 6;
  const int wr = (wv >> 1) * 64, wc = (wv & 1) * 64;
  const int fr = lane & 15, kg = lane >> 4;

  f32x4 acc[4][4];
#pragma unroll
  for (int m = 0; m < 4; ++m)
#pragma unroll
    for (int nn = 0; nn < 4; ++nn) acc[m][nn] = (f32x4){0.f, 0.f, 0.f, 0.f};

  const char* Ab = (const char*)Al;
  const char* Bb = (const char*)Bl;

  for (int kt = 0; kt < DMODEL / 32; ++kt) {
    const int k0 = kt * 32;
    __syncthreads();                        // previous compute done
    gload16(asrc1 + k0, al_dst);
    gload16(asrc2 + k0, al_dst + 256 * 8);
    gload16(bsrc1 + k0, bl_dst);
    gload16(bsrc2 + k0, bl_dst + 256 * 8);
    asm volatile("s_waitcnt vmcnt(0)" ::: "memory");
    __syncthreads();                        // tile visible to all waves
    bf16x8 a[4], b[4];
#pragma unroll
    for (int m = 0; m < 4; ++m)
      a[m] = *(const bf16x8*)(Ab + ((wr + m * 16 + fr) * 32 + kg * 8) * 2);
#pragma unroll
    for (int nn = 0; nn < 4; ++nn)
      b[nn] = *(const bf16x8*)(Bb + ((wc + nn * 16 + fr) * 32 + kg * 8) * 2);
#pragma unroll
    for (int m = 0; m < 4; ++m)
#pragma unroll
      for (int nn = 0; nn < 4; ++nn)
        acc[m][nn] = __builtin_amdgcn_mfma_f32_16x16x32_bf16(a[m], b[nn], acc[m][nn], 0, 0, 0);
  }

  // epilogue: bias + relu -> H[slot][col] bf16. C/D: col=lane&15, row=kg*4+reg.
  const int slot0 = offs[e];
  float bias[4]; int bcol[4];
#pragma unroll
  for (int nn = 0; nn < 4; ++nn) {
    bcol[nn] = cb * 128 + wc + nn * 16 + fr;
    bias[nn] = b1[e * HDIM + bcol[nn]];
  }
#pragma unroll
  for (int m = 0; m < 4; ++m)
#pragma unroll
    for (int j = 0; j < 4; ++j) {
      const int p = rb * 128 + wr + m * 16 + kg * 4 + j;
      if (p < n) {
        bf16* hrow = Hbuf + (size_t)(slot0 + p) * HDIM;
#pragma unroll
        for (int nn = 0; nn < 4; ++nn) {
          float v = acc[m][nn][j] + bias[nn];
          hrow[bcol[nn]] = (bf16)(v > 0.f ? v : 0.f);
        }
      }
    }
}

// ---------------- GEMM2: out[tok] += s * (H @ W2 + b2), fp32 atomic ----------------
__global__ __launch_bounds__(256) void gemm2_kernel(
    const bf16* __restrict__ Hbuf, const bf16* __restrict__ w2t,
    const float* __restrict__ b2, const int* __restrict__ cnt,
    const int* __restrict__ offs, const int* __restrict__ bucket,
    const float* __restrict__ topks, float* __restrict__ out)
{
  const int e  = blockIdx.x >> 8;
  const int rb = blockIdx.x & 255;
  const int n  = cnt[e];
  if (rb * 128 >= n) return;
  const int cb = blockIdx.y;

  __shared__ bf16 Al[128 * 32];
  __shared__ bf16 Bl[128 * 32];

  const int t  = threadIdx.x;
  const int r1 = t >> 2, c8 = (t & 3) * 8;
  const int slot0 = offs[e];
  // contiguous compacted H rows (buffer has 128 rows of slack for the tail)
  const bf16* asrc1 = Hbuf + (size_t)(slot0 + rb * 128 + r1) * HDIM + c8;
  const bf16* asrc2 = asrc1 + (size_t)64 * HDIM;
  const bf16* bsrc1 = w2t + (size_t)e * HDIM * DMODEL
                    + (size_t)(cb * 128 + r1) * HDIM + c8;
  const bf16* bsrc2 = bsrc1 + (size_t)64 * HDIM;
  bf16* al_dst = &Al[t * 8];
  bf16* bl_dst = &Bl[t * 8];

  const int lane = t & 63, wv = t >> 6;
  const int wr = (wv >> 1) * 64, wc = (wv & 1) * 64;
  const int fr = lane & 15, kg = lane >> 4;

  f32x4 acc[4][4];
#pragma unroll
  for (int m = 0; m < 4; ++m)
#pragma unroll
    for (int nn = 0; nn < 4; ++nn) acc[m][nn] = (f32x4){0.f, 0.f, 0.f, 0.f};

  const char* Ab = (const char*)Al;
  const char* Bb = (const char*)Bl;

  for (int kt = 0; kt < HDIM / 32; ++kt) {
    const int k0 = kt * 32;
    __syncthreads();
    gload16(asrc1 + k0, al_dst);
    gload16(asrc2 + k0, al_dst + 256 * 8);
    gload16(bsrc1 + k0, bl_dst);
    gload16(bsrc2 + k0, bl_dst + 256 * 8);
    asm volatile("s_waitcnt vmcnt(0)" ::: "memory");
    __syncthreads();
    bf16x8 a[4], b[4];
#pragma unroll
    for (int m = 0; m < 4; ++m)
      a[m] = *(const bf16x8*)(Ab + ((wr + m * 16 + fr) * 32 + kg * 8) * 2);
#pragma unroll
    for (int nn = 0; nn < 4; ++nn)
      b[nn] = *(const bf16x8*)(Bb + ((wc + nn * 16 + fr) * 32 + kg * 8) * 2);
#pragma unroll
    for (int m = 0; m < 4; ++m)
#pragma unroll
      for (int nn = 0; nn < 4; ++nn)
        acc[m][nn] = __builtin_amdgcn_mfma_f32_16x16x32_bf16(a[m], b[nn], acc[m][nn], 0, 0, 0);
  }

  float bias[4]; int bcol[4];
#pragma unroll
  for (int nn = 0; nn < 4; ++nn) {
    bcol[nn] = cb * 128 + wc + nn * 16 + fr;
    bias[nn] = b2[e * DMODEL + bcol[nn]];
  }
#pragma unroll
  for (int m = 0; m < 4; ++m)
#pragma unroll
    for (int j = 0; j < 4; ++j) {
      const int p = rb * 128 + wr + m * 16 + kg * 4 + j;
      if (p < n) {
        const int entry = bucket[e * NTOK + p];
        const float s = topks[entry];
        float* orow = out + (size_t)(entry >> 1) * DMODEL;
#pragma unroll
        for (int nn = 0; nn < 4; ++nn)
          atomicAdd(&orow[bcol[nn]], s * (acc[m][nn][j] + bias[nn]));
      }
    }
}

extern "C" void kernel_launch(void* const* d_in, const int* in_sizes, int n_in,
                              void* d_out, int out_size, void* d_ws, size_t ws_size,
                              hipStream_t stream)
{
  const float* x  = (const float*)d_in[0];
  const float* gw = (const float*)d_in[1];
  const float* gb = (const float*)d_in[2];
  const float* w1 = (const float*)d_in[3];
  const float* b1 = (const float*)d_in[4];
  const float* w2 = (const float*)d_in[5];
  const float* b2 = (const float*)d_in[6];
  float* out = (float*)d_out;
  char*  ws  = (char*)d_ws;

  if (ws_size < WS_END) return;  // scratch too small: bail cleanly (validation will flag)

  int*   cnt    = (int*)(ws + WS_CNT);
  int*   offs   = (int*)(ws + WS_OFFS);
  int*   bucket = (int*)(ws + WS_BUCKET);
  float* topks  = (float*)(ws + WS_TOPKS);
  bf16*  xb     = (bf16*)(ws + WS_XB);
  bf16*  w1t    = (bf16*)(ws + WS_W1T);
  bf16*  w2t    = (bf16*)(ws + WS_W2T);
  bf16*  Hbuf   = (bf16*)(ws + WS_H);

  hipMemsetAsync(cnt, 0, NEXP * sizeof(int), stream);
  hipMemsetAsync(out, 0, (size_t)NTOK * DMODEL * sizeof(float), stream);

  gate_kernel<<<NTOK / 4, 256, 0, stream>>>(x, gw, gb, cnt, bucket, topks);
  scan_kernel<<<1, 64, 0, stream>>>(cnt, offs);
  cvt_x_kernel<<<2048, 256, 0, stream>>>(x, xb);
  cvt_wt_kernel<<<dim3(1024, NEXP), 256, 0, stream>>>(w1, w1t);
  cvt_wt_kernel<<<dim3(1024, NEXP), 256, 0, stream>>>(w2, w2t);
  gemm1_kernel<<<dim3(NEXP * 256, 8), 256, 0, stream>>>(xb, w1t, b1, cnt, offs, bucket, Hbuf);
  gemm2_kernel<<<dim3(NEXP * 256, 8), 256, 0, stream>>>(Hbuf, w2t, b2, cnt, offs, bucket, topks, out);
}

// Round 2
// 889.109 us; speedup vs baseline: 1.8093x; 1.8093x over previous
//
#include <hip/hip_runtime.h>
#include <hip/hip_bf16.h>
#include <stdint.h>

// Sparse MoE FFN: N=32768 tokens, D=H=1024, E=8, top-2, fp32 in/out.
// Pipeline: fp32 gate+top2 (LDS-aggregated bucketing, fused x->bf16) ->
// bf16 MFMA GEMM1 (relu) -> bf16 MFMA GEMM2 -> weighted fp32 atomic add.

#define NTOK  32768
#define DMODEL 1024
#define HDIM   1024
#define NEXP      8

typedef __bf16 bf16;
typedef __bf16 bf16x4 __attribute__((ext_vector_type(4)));
typedef __bf16 bf16x8 __attribute__((ext_vector_type(8)));
typedef float  f32x4  __attribute__((ext_vector_type(4)));

// ---- workspace layout (bytes), all regions 256B-aligned ----
static constexpr size_t WS_CNT    = 0;                                        // 8 int
static constexpr size_t WS_OFFS   = 256;                                      // 8 int
static constexpr size_t WS_BUCKET = 512;                                      // [E][NTOK] int (entry = tok*2+k)
static constexpr size_t WS_TOPKS  = WS_BUCKET + (size_t)NEXP * NTOK * 4;      // [NTOK*2] float
static constexpr size_t WS_XB     = WS_TOPKS + (size_t)NTOK * 2 * 4;          // x in bf16 [NTOK][D]
static constexpr size_t WS_W1T    = WS_XB  + (size_t)NTOK * DMODEL * 2;       // w1^T bf16 [E][H][D]
static constexpr size_t WS_W2T    = WS_W1T + (size_t)NEXP * DMODEL * HDIM * 2;// w2^T bf16 [E][D][H]
static constexpr size_t WS_H      = WS_W2T + (size_t)NEXP * HDIM * DMODEL * 2;// H bf16 [2N+128][H]
static constexpr size_t WS_END    = WS_H   + (size_t)(2 * NTOK + 128) * HDIM * 2; // ~226 MiB

// async global->LDS, 16B per lane. LDS dest is wave-uniform base + lane*16;
// we pass per-lane &lds[t*8] whose lane-0 value IS the wave base (linear fill).
__device__ __forceinline__ void gload16(const void* g, void* l) {
  __builtin_amdgcn_global_load_lds(
      (const __attribute__((address_space(1))) unsigned int*)(uintptr_t)g,
      (__attribute__((address_space(3))) unsigned int*)(uintptr_t)l,
      16, 0, 0);
}

// ---------------- gating: fp32 scores, exact top-2, LDS-aggregated buckets ----
// 512 blocks x 64 tokens. Wave w handles tokens w*16..w*16+15 (one wave/token
// dot, float4 x loads fused with bf16 conversion). Ranks via LDS atomics;
// 8 global atomics per block total.
__global__ __launch_bounds__(256) void gate_kernel(
    const float* __restrict__ x, const float* __restrict__ gw,
    const float* __restrict__ gb, int* __restrict__ cnt,
    int* __restrict__ bucket, float* __restrict__ topks,
    bf16* __restrict__ xb)
{
  __shared__ int lcnt[NEXP];
  __shared__ int lbase[NEXP];
  __shared__ short ti_i1[64], ti_i2[64], ti_r1[64], ti_r2[64];

  const int t = threadIdx.x;
  if (t < NEXP) lcnt[t] = 0;
  __syncthreads();

  const int lane = t & 63;
  const int wv   = t >> 6;
  const int t0   = blockIdx.x * 64;

  for (int i = 0; i < 16; ++i) {
    const int tt  = wv * 16 + i;
    const int tok = t0 + tt;
    const float4* xr4 = (const float4*)(x + (size_t)tok * DMODEL);
    bf16x4*       xbr = (bf16x4*)(xb + (size_t)tok * DMODEL);

    float sc[NEXP];
#pragma unroll
    for (int e = 0; e < NEXP; ++e) sc[e] = 0.f;

#pragma unroll
    for (int it = 0; it < 4; ++it) {
      const int q = it * 64 + lane;          // float4 index within the row
      float4 v = xr4[q];
      bf16x4 o = { (bf16)v.x, (bf16)v.y, (bf16)v.z, (bf16)v.w };
      xbr[q] = o;                            // fused fp32->bf16 conversion
      const float* g = gw + (size_t)q * 4 * NEXP;
      const float vv[4] = { v.x, v.y, v.z, v.w };
#pragma unroll
      for (int j = 0; j < 4; ++j)
#pragma unroll
        for (int e = 0; e < NEXP; ++e)
          sc[e] += vv[j] * g[j * NEXP + e];
    }
#pragma unroll
    for (int e = 0; e < NEXP; ++e) {
      float a = sc[e];
#pragma unroll
      for (int off = 32; off; off >>= 1) a += __shfl_xor(a, off);
      sc[e] = a + gb[e];
    }

    if (lane == 0) {
      // strict > keeps the lowest index on ties == lax.top_k semantics
      int i1 = 0; float s1 = sc[0];
#pragma unroll
      for (int e = 1; e < NEXP; ++e) if (sc[e] > s1) { s1 = sc[e]; i1 = e; }
      int i2 = (i1 == 0) ? 1 : 0; float s2 = sc[i2];
#pragma unroll
      for (int e = 0; e < NEXP; ++e)
        if (e != i1 && sc[e] > s2) { s2 = sc[e]; i2 = e; }
      ti_i1[tt] = (short)i1; ti_r1[tt] = (short)atomicAdd(&lcnt[i1], 1);
      ti_i2[tt] = (short)i2; ti_r2[tt] = (short)atomicAdd(&lcnt[i2], 1);
      topks[tok * 2]     = s1;
      topks[tok * 2 + 1] = s2;
    }
  }
  __syncthreads();
  if (t < NEXP) lbase[t] = atomicAdd(&cnt[t], lcnt[t]);
  __syncthreads();
  if (t < 128) {
    const int tt = t >> 1, k = t & 1;
    const int e  = k ? ti_i2[tt] : ti_i1[tt];
    const int r  = k ? ti_r2[tt] : ti_r1[tt];
    bucket[e * NTOK + lbase[e] + r] = (t0 + tt) * 2 + k;
  }
}

__global__ void scan_kernel(const int* __restrict__ cnt, int* __restrict__ offs) {
  if (threadIdx.x == 0) {
    int r = 0;
    for (int e = 0; e < NEXP; ++e) { offs[e] = r; r += cnt[e]; }
  }
}

// w[e][k][n] fp32 -> wt[e][n][k] bf16 (transpose so GEMM B-frags are K-contiguous)
__global__ __launch_bounds__(256) void cvt_wt_kernel(
    const float* __restrict__ w, bf16* __restrict__ wt)
{
  __shared__ float tile[32][33];
  const int e  = blockIdx.y;
  const int tk = (blockIdx.x >> 5) * 32;  // source row (k) base
  const int tn = (blockIdx.x & 31) * 32;  // source col (n) base
  const int r  = threadIdx.x >> 3, c4 = (threadIdx.x & 7) * 4;
  const float* we = w + (size_t)e * DMODEL * HDIM;
  float4 v = *(const float4*)&we[(size_t)(tk + r) * 1024 + tn + c4];
  tile[r][c4 + 0] = v.x; tile[r][c4 + 1] = v.y;
  tile[r][c4 + 2] = v.z; tile[r][c4 + 3] = v.w;
  __syncthreads();
  bf16x4 o = { (bf16)tile[c4 + 0][r], (bf16)tile[c4 + 1][r],
               (bf16)tile[c4 + 2][r], (bf16)tile[c4 + 3][r] };
  *(bf16x4*)&wt[(size_t)e * DMODEL * HDIM + (size_t)(tn + r) * 1024 + tk + c4] = o;
}

// ---------------- GEMM1: H = relu(X[bucket] @ W1 + b1), bf16 out ----------------
__global__ __launch_bounds__(256) void gemm1_kernel(
    const bf16* __restrict__ xb, const bf16* __restrict__ w1t,
    const float* __restrict__ b1, const int* __restrict__ cnt,
    const int* __restrict__ offs, const int* __restrict__ bucket,
    bf16* __restrict__ Hbuf)
{
  const int e  = blockIdx.x >> 8;
  const int rb = blockIdx.x & 255;
  const int n  = cnt[e];
  if (rb * 128 >= n) return;
  const int cb = blockIdx.y;

  __shared__ bf16 Al[128 * 32];
  __shared__ bf16 Bl[128 * 32];

  const int t  = threadIdx.x;
  const int r1 = t >> 2, c8 = (t & 3) * 8;
  const int p1 = rb * 128 + r1, p2 = p1 + 64;
  const int ent1 = bucket[e * NTOK + (p1 < n ? p1 : n - 1)];
  const int ent2 = bucket[e * NTOK + (p2 < n ? p2 : n - 1)];
  const bf16* asrc1 = xb + (size_t)(ent1 >> 1) * DMODEL + c8;   // gathered rows
  const bf16* asrc2 = xb + (size_t)(ent2 >> 1) * DMODEL + c8;
  const bf16* bsrc1 = w1t + (size_t)e * DMODEL * HDIM
                    + (size_t)(cb * 128 + r1) * DMODEL + c8;
  const bf16* bsrc2 = bsrc1 + (size_t)64 * DMODEL;
  bf16* al_dst = &Al[t * 8];
  bf16* bl_dst = &Bl[t * 8];

  const int lane = t & 63, wv = t >> 6;
  const int wr = (wv >> 1) * 64, wc = (wv & 1) * 64;
  const int fr = lane & 15, kg = lane >> 4;

  f32x4 acc[4][4];
#pragma unroll
  for (int m = 0; m < 4; ++m)
#pragma unroll
    for (int nn = 0; nn < 4; ++nn) acc[m][nn] = (f32x4){0.f, 0.f, 0.f, 0.f};

  const char* Ab = (const char*)Al;
  const char* Bb = (const char*)Bl;

  for (int kt = 0; kt < DMODEL / 32; ++kt) {
    const int k0 = kt * 32;
    __syncthreads();                        // previous compute done
    gload16(asrc1 + k0, al_dst);
    gload16(asrc2 + k0, al_dst + 256 * 8);
    gload16(bsrc1 + k0, bl_dst);
    gload16(bsrc2 + k0, bl_dst + 256 * 8);
    asm volatile("s_waitcnt vmcnt(0)" ::: "memory");
    __syncthreads();                        // tile visible to all waves
    bf16x8 a[4], b[4];
#pragma unroll
    for (int m = 0; m < 4; ++m)
      a[m] = *(const bf16x8*)(Ab + ((wr + m * 16 + fr) * 32 + kg * 8) * 2);
#pragma unroll
    for (int nn = 0; nn < 4; ++nn)
      b[nn] = *(const bf16x8*)(Bb + ((wc + nn * 16 + fr) * 32 + kg * 8) * 2);
#pragma unroll
    for (int m = 0; m < 4; ++m)
#pragma unroll
      for (int nn = 0; nn < 4; ++nn)
        acc[m][nn] = __builtin_amdgcn_mfma_f32_16x16x32_bf16(a[m], b[nn], acc[m][nn], 0, 0, 0);
  }

  // epilogue: bias + relu -> H[slot][col] bf16. C/D: col=lane&15, row=kg*4+reg.
  const int slot0 = offs[e];
  float bias[4]; int bcol[4];
#pragma unroll
  for (int nn = 0; nn < 4; ++nn) {
    bcol[nn] = cb * 128 + wc + nn * 16 + fr;
    bias[nn] = b1[e * HDIM + bcol[nn]];
  }
#pragma unroll
  for (int m = 0; m < 4; ++m)
#pragma unroll
    for (int j = 0; j < 4; ++j) {
      const int p = rb * 128 + wr + m * 16 + kg * 4 + j;
      if (p < n) {
        bf16* hrow = Hbuf + (size_t)(slot0 + p) * HDIM;
#pragma unroll
        for (int nn = 0; nn < 4; ++nn) {
          float v = acc[m][nn][j] + bias[nn];
          hrow[bcol[nn]] = (bf16)(v > 0.f ? v : 0.f);
        }
      }
    }
}

// ---------------- GEMM2: out[tok] += s * (H @ W2 + b2), fp32 atomic ----------------
__global__ __launch_bounds__(256) void gemm2_kernel(
    const bf16* __restrict__ Hbuf, const bf16* __restrict__ w2t,
    const float* __restrict__ b2, const int* __restrict__ cnt,
    const int* __restrict__ offs, const int* __restrict__ bucket,
    const float* __restrict__ topks, float* __restrict__ out)
{
  const int e  = blockIdx.x >> 8;
  const int rb = blockIdx.x & 255;
  const int n  = cnt[e];
  if (rb * 128 >= n) return;
  const int cb = blockIdx.y;

  __shared__ bf16 Al[128 * 32];
  __shared__ bf16 Bl[128 * 32];

  const int t  = threadIdx.x;
  const int r1 = t >> 2, c8 = (t & 3) * 8;
  const int slot0 = offs[e];
  // contiguous compacted H rows (buffer has 128 rows of slack for the tail)
  const bf16* asrc1 = Hbuf + (size_t)(slot0 + rb * 128 + r1) * HDIM + c8;
  const bf16* asrc2 = asrc1 + (size_t)64 * HDIM;
  const bf16* bsrc1 = w2t + (size_t)e * HDIM * DMODEL
                    + (size_t)(cb * 128 + r1) * HDIM + c8;
  const bf16* bsrc2 = bsrc1 + (size_t)64 * HDIM;
  bf16* al_dst = &Al[t * 8];
  bf16* bl_dst = &Bl[t * 8];

  const int lane = t & 63, wv = t >> 6;
  const int wr = (wv >> 1) * 64, wc = (wv & 1) * 64;
  const int fr = lane & 15, kg = lane >> 4;

  f32x4 acc[4][4];
#pragma unroll
  for (int m = 0; m < 4; ++m)
#pragma unroll
    for (int nn = 0; nn < 4; ++nn) acc[m][nn] = (f32x4){0.f, 0.f, 0.f, 0.f};

  const char* Ab = (const char*)Al;
  const char* Bb = (const char*)Bl;

  for (int kt = 0; kt < HDIM / 32; ++kt) {
    const int k0 = kt * 32;
    __syncthreads();
    gload16(asrc1 + k0, al_dst);
    gload16(asrc2 + k0, al_dst + 256 * 8);
    gload16(bsrc1 + k0, bl_dst);
    gload16(bsrc2 + k0, bl_dst + 256 * 8);
    asm volatile("s_waitcnt vmcnt(0)" ::: "memory");
    __syncthreads();
    bf16x8 a[4], b[4];
#pragma unroll
    for (int m = 0; m < 4; ++m)
      a[m] = *(const bf16x8*)(Ab + ((wr + m * 16 + fr) * 32 + kg * 8) * 2);
#pragma unroll
    for (int nn = 0; nn < 4; ++nn)
      b[nn] = *(const bf16x8*)(Bb + ((wc + nn * 16 + fr) * 32 + kg * 8) * 2);
#pragma unroll
    for (int m = 0; m < 4; ++m)
#pragma unroll
      for (int nn = 0; nn < 4; ++nn)
        acc[m][nn] = __builtin_amdgcn_mfma_f32_16x16x32_bf16(a[m], b[nn], acc[m][nn], 0, 0, 0);
  }

  float bias[4]; int bcol[4];
#pragma unroll
  for (int nn = 0; nn < 4; ++nn) {
    bcol[nn] = cb * 128 + wc + nn * 16 + fr;
    bias[nn] = b2[e * DMODEL + bcol[nn]];
  }
#pragma unroll
  for (int m = 0; m < 4; ++m)
#pragma unroll
    for (int j = 0; j < 4; ++j) {
      const int p = rb * 128 + wr + m * 16 + kg * 4 + j;
      if (p < n) {
        const int entry = bucket[e * NTOK + p];
        const float s = topks[entry];
        float* orow = out + (size_t)(entry >> 1) * DMODEL;
#pragma unroll
        for (int nn = 0; nn < 4; ++nn)
          atomicAdd(&orow[bcol[nn]], s * (acc[m][nn][j] + bias[nn]));
      }
    }
}

extern "C" void kernel_launch(void* const* d_in, const int* in_sizes, int n_in,
                              void* d_out, int out_size, void* d_ws, size_t ws_size,
                              hipStream_t stream)
{
  const float* x  = (const float*)d_in[0];
  const float* gw = (const float*)d_in[1];
  const float* gb = (const float*)d_in[2];
  const float* w1 = (const float*)d_in[3];
  const float* b1 = (const float*)d_in[4];
  const float* w2 = (const float*)d_in[5];
  const float* b2 = (const float*)d_in[6];
  float* out = (float*)d_out;
  char*  ws  = (char*)d_ws;

  if (ws_size < WS_END) return;  // scratch too small: bail cleanly (validation will flag)

  int*   cnt    = (int*)(ws + WS_CNT);
  int*   offs   = (int*)(ws + WS_OFFS);
  int*   bucket = (int*)(ws + WS_BUCKET);
  float* topks  = (float*)(ws + WS_TOPKS);
  bf16*  xb     = (bf16*)(ws + WS_XB);
  bf16*  w1t    = (bf16*)(ws + WS_W1T);
  bf16*  w2t    = (bf16*)(ws + WS_W2T);
  bf16*  Hbuf   = (bf16*)(ws + WS_H);

  hipMemsetAsync(cnt, 0, NEXP * sizeof(int), stream);
  hipMemsetAsync(out, 0, (size_t)NTOK * DMODEL * sizeof(float), stream);

  gate_kernel<<<NTOK / 64, 256, 0, stream>>>(x, gw, gb, cnt, bucket, topks, xb);
  scan_kernel<<<1, 64, 0, stream>>>(cnt, offs);
  cvt_wt_kernel<<<dim3(1024, NEXP), 256, 0, stream>>>(w1, w1t);
  cvt_wt_kernel<<<dim3(1024, NEXP), 256, 0, stream>>>(w2, w2t);
  gemm1_kernel<<<dim3(NEXP * 256, 8), 256, 0, stream>>>(xb, w1t, b1, cnt, offs, bucket, Hbuf);
  gemm2_kernel<<<dim3(NEXP * 256, 8), 256, 0, stream>>>(Hbuf, w2t, b2, cnt, offs, bucket, topks, out);
}